// Round 11
// baseline (137.597 us; speedup 1.0000x reference)
//
#include <hip/hip_runtime.h>
#include <stdint.h>

// Bert4Argument: out[b,l,c] = sum_f feat[b,l,f] * W[c,f] + b[c]
// feat = [ seq[i, head[i,l], :] | pos_emb[l-pos[i]+256, :] | class_emb[(l==pos[i])?frame[i]:0, :] ]
// B=64, L=256, D=768 -> M=16384, K=2304, N=200 (padded to 8 tiles of 32 = 256)
//
// R11: R7's proven structure (bf16 mirrors + packed W, all-DMA staging,
// 2-barrier chunk loop) but with 32x32x16 MFMA and a 2x2 fragment tile:
// 4 ds_read_b128 -> 4 MFMAs of 32K FLOP = 2x fewer LDS reads per FLOP
// (the LDS read port was gemm6's floor). Block = 128 thr / 2 waves,
// 64 rows x 128 cols; grid 512; LDS 24 KB -> ~6 blocks/CU to hide drains.
//
// 32x32x16 layouts: A/B operand: lane = m(n) + 32*(k/8), elem j = k%8.
// C/D (HW-verified m74/m101): col = lane&31, row = (reg&3)+8*(reg>>2)+4*(lane>>5).

typedef __attribute__((ext_vector_type(8))) short short8;
typedef __attribute__((ext_vector_type(4))) float f32x4;
typedef __attribute__((ext_vector_type(16))) float f32x16;

#define AS1 __attribute__((address_space(1)))
#define AS3 __attribute__((address_space(3)))

#define NSEQ_G 1572864   // 64*256*768/8
#define NPE_G  49248     // 513*768/8
#define NCE_G  19296     // 201*768/8
#define NW32_G 73728     // 8*288*32
#define SEQB_OFF 0
#define PEB_OFF  12582912
#define CEB_OFF  (PEB_OFF + 393984)     // 12,976,896
#define WP_OFF   (CEB_OFF + 154368)     // 13,131,264
#define WS_ELEMS (WP_OFF + 589824)      // 13,721,088
#define WS_NEED  ((size_t)WS_ELEMS * 2) // 27,442,176 B
#define T32_STRIDE 73728                // 288*32*8 shorts per 32-col tile

__device__ __forceinline__ unsigned short f2bf(float f) {
    union { float f; unsigned int u; } v; v.f = f;
    unsigned int u = v.u;
    return (unsigned short)((u + 0x7fffu + ((u >> 16) & 1u)) >> 16);
}

__device__ __forceinline__ short8 pack8(f32x4 a, f32x4 b) {
    short8 r;
    r[0] = (short)f2bf(a.x); r[1] = (short)f2bf(a.y);
    r[2] = (short)f2bf(a.z); r[3] = (short)f2bf(a.w);
    r[4] = (short)f2bf(b.x); r[5] = (short)f2bf(b.y);
    r[6] = (short)f2bf(b.z); r[7] = (short)f2bf(b.w);
    return r;
}

__device__ __forceinline__ void dma16(const unsigned short* g, AS3 unsigned short* l) {
    __builtin_amdgcn_global_load_lds((AS1 const unsigned int*)g,
                                     (AS3 unsigned int*)l, 16, 0, 0);
}

// ---------------------------------------------------------------------------
// Prep: bf16 mirrors of seq/pe/ce; pack W f32 [200][2304] -> bf16 in 32-col
// tiles (rows >= 200 zero): Wp[((t*288+k8)*32+n)*8+j] = W[t*32+n][k8*8+j]
// ---------------------------------------------------------------------------
__global__ void prep_kernel(const float* __restrict__ seq,
                            const float* __restrict__ pe,
                            const float* __restrict__ ce,
                            const float* __restrict__ W,
                            unsigned short* __restrict__ ws) {
    int g = blockIdx.x * 256 + threadIdx.x;
    if (g < NSEQ_G) {
        const float* p = seq + (size_t)g * 8;
        *(short8*)(ws + SEQB_OFF + (size_t)g * 8) =
            pack8(*(const f32x4*)p, *(const f32x4*)(p + 4));
        return;
    }
    g -= NSEQ_G;
    if (g < NPE_G) {
        const float* p = pe + (size_t)g * 8;
        *(short8*)(ws + PEB_OFF + (size_t)g * 8) =
            pack8(*(const f32x4*)p, *(const f32x4*)(p + 4));
        return;
    }
    g -= NPE_G;
    if (g < NCE_G) {
        const float* p = ce + (size_t)g * 8;
        *(short8*)(ws + CEB_OFF + (size_t)g * 8) =
            pack8(*(const f32x4*)p, *(const f32x4*)(p + 4));
        return;
    }
    g -= NCE_G;
    if (g < NW32_G) {
        int n  = g & 31;
        int k8 = (g >> 5) % 288;
        int t  = g / (288 * 32);
        int row = t * 32 + n;
        int col = k8 * 8;
        f32x4 a = {0.f, 0.f, 0.f, 0.f}, b = {0.f, 0.f, 0.f, 0.f};
        if (row < 200) {
            const float* p = W + (size_t)row * 2304 + col;
            a = *(const f32x4*)p;
            b = *(const f32x4*)(p + 4);
        }
        *(short8*)(ws + WP_OFF + (size_t)g * 8) = pack8(a, b);
    }
}

// ---------------------------------------------------------------------------
// GEMM: grid 512 x 128 thr (2 waves). mblk = blockIdx&255 -> rows [64m,+64),
// nh = blockIdx>>8 -> cols [128nh, +128) (4 tiles of 32). Batch i = mblk>>2.
// K-chunk 64 (36 chunks, 3 segs x 12).
// LDS: A[f][kb][lane][8] (f=m-frag 0..1, kb=k16-block 0..3) = 4096 shorts;
//      B[s][kb][lane][8] (s=local tile 0..3) = 8192 shorts at +4096... (sep array)
// Staging per wave: A frag f=wave (4 dma), B tiles {2w,2w+1} (8 dma).
// Compute per wave: frags {0,1} x tiles {2w,2w+1}; 4 kb x (4 reads, 4 MFMA).
// ---------------------------------------------------------------------------
__global__ __launch_bounds__(128) void gemm10_kernel(
    const unsigned short* __restrict__ ws,
    const float* __restrict__ bias,
    const int*   __restrict__ head,
    const int*   __restrict__ frame,
    const int*   __restrict__ pos,
    float* __restrict__ out)
{
    __shared__ unsigned short ldsA[4096];   //  8 KB
    __shared__ unsigned short ldsB[8192];   // 16 KB

    const unsigned short* seqb = ws + SEQB_OFF;
    const unsigned short* peb  = ws + PEB_OFF;
    const unsigned short* ceb  = ws + CEB_OFF;
    const unsigned short* Wp   = ws + WP_OFF;

    const int tid  = threadIdx.x;
    const int wave = tid >> 6;
    const int lane = tid & 63;
    const int n32  = lane & 31;
    const int half = lane >> 5;

    const int mblk = blockIdx.x & 255;
    const int nh   = blockIdx.x >> 8;

    const int i       = mblk >> 2;
    const int pos_i   = pos[i];
    const int frame_i = frame[i];

    // ---- A staging: wave stages m-frag f = wave; lane: row n32, k-off half*8
    const int arow = mblk * 64 + wave * 32 + n32;
    const unsigned short *aSeg[3];
    {
        const int aj   = arow & 255;
        const int ahi  = head[arow];
        const int arel = aj - pos_i + 256;                 // [1, 511]
        const int acls = (aj == pos_i) ? frame_i : 0;
        const int loff = half * 8;
        aSeg[0] = seqb + ((size_t)i * 256 + (size_t)ahi) * 768 + loff;
        aSeg[1] = peb + (size_t)arel * 768 + loff;
        aSeg[2] = ceb + (size_t)acls * 768 + loff;
    }
    AS3 unsigned short* aD = (AS3 unsigned short*)ldsA + wave * 2048 + lane * 8;

    // ---- B staging: wave stages local tiles {2w, 2w+1} (global nh*4 + ...)
    const unsigned short* bSt0 = Wp + (size_t)(nh * 4 + 2 * wave) * T32_STRIDE + lane * 8;
    const unsigned short* bSt1 = bSt0 + T32_STRIDE;
    AS3 unsigned short* bD = (AS3 unsigned short*)ldsB + (2 * wave) * 2048 + lane * 8;

    // ---- accumulators (wave computes frags {0,1} x local tiles {2w, 2w+1})
    f32x16 acc[2][2];
#pragma unroll
    for (int ni = 0; ni < 2; ++ni) {
        const int col = nh * 128 + (2 * wave + ni) * 32 + n32;
        const float bv = (col < 200) ? bias[col] : 0.0f;
#pragma unroll
        for (int f = 0; f < 2; ++f)
#pragma unroll
            for (int r = 0; r < 16; ++r) acc[f][ni][r] = bv;
    }

    const int bRd0 = (2 * wave) * 2048 + lane * 8;   // + kb*512 (+2048 for ni=1)

#pragma unroll
    for (int sg = 0; sg < 3; ++sg) {
        const unsigned short* aSrc = aSeg[sg];
        for (int cc = 0; cc < 12; ++cc) {
            const int c = sg * 12 + cc;
            // stage: 4 A dma (kb 0..3) + 8 B dma (2 tiles x 4)
#pragma unroll
            for (int kb = 0; kb < 4; ++kb)
                dma16(aSrc + cc * 64 + kb * 16, aD + kb * 512);
#pragma unroll
            for (int r = 0; r < 4; ++r) {
                dma16(bSt0 + (size_t)c * 2048 + r * 512, bD + r * 512);
                dma16(bSt1 + (size_t)c * 2048 + r * 512, bD + 2048 + r * 512);
            }
            __syncthreads();
            // compute: 4 kb x (2 A + 2 B reads -> 4 MFMA 32x32x16)
#pragma unroll
            for (int kb = 0; kb < 4; ++kb) {
                short8 a0 = *(const short8*)(ldsA + kb * 512 + lane * 8);
                short8 a1 = *(const short8*)(ldsA + 2048 + kb * 512 + lane * 8);
                short8 b0 = *(const short8*)(ldsB + bRd0 + kb * 512);
                short8 b1 = *(const short8*)(ldsB + bRd0 + 2048 + kb * 512);
                acc[0][0] = __builtin_amdgcn_mfma_f32_32x32x16_bf16(a0, b0, acc[0][0], 0, 0, 0);
                acc[1][0] = __builtin_amdgcn_mfma_f32_32x32x16_bf16(a1, b0, acc[1][0], 0, 0, 0);
                acc[0][1] = __builtin_amdgcn_mfma_f32_32x32x16_bf16(a0, b1, acc[0][1], 0, 0, 0);
                acc[1][1] = __builtin_amdgcn_mfma_f32_32x32x16_bf16(a1, b1, acc[1][1], 0, 0, 0);
            }
            __syncthreads();
        }
    }

    // epilogue: C/D col = lane&31, row = (reg&3) + 8*(reg>>2) + 4*(lane>>5)
#pragma unroll
    for (int f = 0; f < 2; ++f) {
        const int rb = mblk * 64 + f * 32 + 4 * half;
#pragma unroll
        for (int ni = 0; ni < 2; ++ni) {
            const int col = nh * 128 + (2 * wave + ni) * 32 + n32;
            if (col < 200) {
#pragma unroll
                for (int r = 0; r < 16; ++r) {
                    const int row = rb + (r & 3) + 8 * (r >> 2);
                    out[(size_t)row * 200 + col] = acc[f][ni][r];
                }
            }
        }
    }
}

// ---------------------------------------------------------------------------
// Fallback (no workspace): slow but correct, f32 W converted inline.
// ---------------------------------------------------------------------------
__global__ __launch_bounds__(256) void gemm_fallback(
    const float* __restrict__ seq, const float* __restrict__ pe,
    const float* __restrict__ ce, const float* __restrict__ Wf,
    const float* __restrict__ bias, const int* __restrict__ head,
    const int* __restrict__ frame, const int* __restrict__ pos,
    float* __restrict__ out)
{
    const int tid  = threadIdx.x;
    const int wave = tid >> 6;
    const int lane = tid & 63;
    const int n16  = lane & 15;
    const int quad = lane >> 4;

    const int mrow  = blockIdx.x * 16 + n16;
    const int i     = mrow >> 8;
    const int j     = mrow & 255;
    const int pos_i = pos[i];
    const int hi    = head[mrow];
    const int rel   = j - pos_i + 256;
    const int cls   = (j == pos_i) ? frame[i] : 0;

    const float* segs[3];
    segs[0] = seq + ((size_t)i * 256 + (size_t)hi) * 768 + quad * 8;
    segs[1] = pe + (size_t)rel * 768 + quad * 8;
    segs[2] = ce + (size_t)cls * 768 + quad * 8;

    const int ntl = (wave == 0) ? 4 : 3;
    f32x4 acc[4];
#pragma unroll
    for (int u = 0; u < 4; ++u) {
        const int t = wave + 4 * u;
        const int col = t * 16 + n16;
        const float bv = (t < 13 && col < 200) ? bias[col] : 0.0f;
        acc[u] = (f32x4){bv, bv, bv, bv};
    }

    for (int s = 0; s < 3; ++s) {
        const float* ap = segs[s];
#pragma unroll 2
        for (int kk = 0; kk < 768; kk += 32) {
            short8 afr = pack8(*(const f32x4*)(ap + kk), *(const f32x4*)(ap + kk + 4));
#pragma unroll
            for (int u = 0; u < 4; ++u) {
                if (u < ntl) {
                    const int t = wave + 4 * u;
                    const int row = t * 16 + n16;
                    short8 bfr = {0, 0, 0, 0, 0, 0, 0, 0};
                    if (row < 200) {
                        const float* qp = Wf + (size_t)row * 2304 + s * 768 + kk + quad * 8;
                        bfr = pack8(*(const f32x4*)qp, *(const f32x4*)(qp + 4));
                    }
                    acc[u] = __builtin_amdgcn_mfma_f32_16x16x32_bf16(afr, bfr, acc[u], 0, 0, 0);
                }
            }
        }
    }

    const int rbase = blockIdx.x * 16 + quad * 4;
#pragma unroll
    for (int u = 0; u < 4; ++u) {
        const int t = wave + 4 * u;
        if (t < 13) {
            const int col = t * 16 + n16;
            if (col < 200) {
#pragma unroll
                for (int r = 0; r < 4; ++r)
                    out[(size_t)(rbase + r) * 200 + col] = acc[u][r];
            }
        }
    }
}

// ---------------------------------------------------------------------------
extern "C" void kernel_launch(void* const* d_in, const int* in_sizes, int n_in,
                              void* d_out, int out_size, void* d_ws, size_t ws_size,
                              hipStream_t stream) {
    const float* seq  = (const float*)d_in[0];
    const float* pe   = (const float*)d_in[1];
    const float* ce   = (const float*)d_in[2];
    const float* W    = (const float*)d_in[3];
    const float* bias = (const float*)d_in[4];
    const int* head   = (const int*)d_in[5];
    const int* frame  = (const int*)d_in[6];
    const int* pos    = (const int*)d_in[7];
    float* out = (float*)d_out;

    if (d_ws != nullptr && ws_size >= WS_NEED) {
        unsigned short* ws = (unsigned short*)d_ws;
        const int total_g = NSEQ_G + NPE_G + NCE_G + NW32_G;   // 1,715,136
        prep_kernel<<<(total_g + 255) / 256, 256, 0, stream>>>(seq, pe, ce, W, ws);
        gemm10_kernel<<<512, 128, 0, stream>>>(ws, bias, head, frame, pos, out);
    } else {
        gemm_fallback<<<1024, 256, 0, stream>>>(seq, pe, ce, W, bias, head,
                                                frame, pos, out);
    }
}